// Round 4
// baseline (288.085 us; speedup 1.0000x reference)
//
#include <hip/hip_runtime.h>
#include <math.h>

#define NQ 1024
#define NR 100000
#define D  128
#define K  8
#define NCH   64          // ref chunks
#define CHUNK 1563        // ceil(NR/NCH)
#define TR    32          // staged ref rows per tile
#define NT    49          // ceil(CHUNK/TR)
#define QPW   32          // queries per wave (2 MFMA q-tiles)

typedef __attribute__((ext_vector_type(8))) short short8;
typedef __attribute__((ext_vector_type(4))) float f32x4;

static __device__ __forceinline__ unsigned short f2bf(float f) {
    unsigned int u = __float_as_uint(f);            // RTNE f32 -> bf16
    return (unsigned short)((u + 0x7FFFu + ((u >> 16) & 1u)) >> 16);
}
static __device__ __forceinline__ float bf2f(unsigned short h) {
    return __uint_as_float(((unsigned int)h) << 16);
}

// sorted-ascending top-K(smallest) insert, branch-guarded (rare after warmup)
__device__ __forceinline__ void topk_insert(float (&t)[K], float d) {
    if (d < t[K - 1]) {
#pragma unroll
        for (int j = K - 1; j > 0; --j)
            t[j] = (d >= t[j]) ? t[j] : ((d < t[j - 1]) ? t[j - 1] : d);
        t[0] = (d < t[0]) ? d : t[0];
    }
}

// ---------------- main kernel: bf16-split MFMA distance + per-chunk top-8 ----
// grid = 4 q-groups x 64 ref-chunks = 256 blocks (1/CU); block = 512 (8 waves).
// 3-term bf16 split: a.b ~= ah.bh + ah.bl + al.bh (drop al.bl, ~2^-17 rel).
// C = mfma(A=refs16, B=queries16): C col = lane&15 (query), rows (lane>>4)*4+reg
// (refs) -> each lane's topk tracks exactly ONE query per q-tile.
// A and B use the SAME assumed k-map (k = 8*(lane>>4)+j); any HW deviation is a
// shared k-permutation and cancels in the dot product.
// Balance: per Ah+Al LDS pair (2 KiB) -> 6 MFMAs = 48 flop/B vs 39.7 needed
// (3377 flop/cy/CU MFMA, 85 B/cy/CU LDS) -> compute-bound 1.2x.
__global__ __launch_bounds__(512, 2) void knn_mfma(const float* __restrict__ x,
                                                   const float* __restrict__ base,
                                                   float* __restrict__ cand) {
    __shared__ unsigned short lhs[2][TR * 128];   // hi bf16, XOR slot-swizzled
    __shared__ unsigned short lls[2][TR * 128];   // lo bf16, XOR slot-swizzled
    __shared__ float lbn[2][TR];                  // ref row norms (INF = excluded)

    const int tid  = threadIdx.x;
    const int lane = tid & 63;
    const int w    = tid >> 6;          // wave 0..7
    const int lm   = lane & 15;         // operand row/col within 16
    const int kg   = lane >> 4;         // k-group 0..3
    const int qb   = blockIdx.x & 3;
    const int rc   = blockIdx.x >> 2;
    const int r0   = rc * CHUNK;
    const int rend = (r0 + CHUNK < NR) ? (r0 + CHUNK) : NR;   // chunk-exclusive bound

    // ---- B-frags: this wave's 32 queries, scaled by -2, split hi/lo bf16 ----
    short8 Bh[2][4], Bl[2][4];
    float  xn[2];
#pragma unroll
    for (int qt = 0; qt < 2; ++qt) {
        const int q = qb * 256 + w * QPW + qt * 16 + lm;
        float s2 = 0.f;
#pragma unroll
        for (int s = 0; s < 4; ++s) {
            const float4 a = *(const float4*)(x + (size_t)q * D + s * 32 + kg * 8);
            const float4 b = *(const float4*)(x + (size_t)q * D + s * 32 + kg * 8 + 4);
            float v[8] = {a.x, a.y, a.z, a.w, b.x, b.y, b.z, b.w};
            short8 hh, ll;
#pragma unroll
            for (int j = 0; j < 8; ++j) {
                s2 = fmaf(v[j], v[j], s2);
                const float m2 = -2.f * v[j];            // exact (pow2 scale)
                const unsigned short h = f2bf(m2);
                const float r = m2 - bf2f(h);            // exact residual
                hh[j] = (short)h;
                ll[j] = (short)f2bf(r);
            }
            Bh[qt][s] = hh; Bl[qt][s] = ll;
        }
        // full ||x||^2: reduce across the 4 k-groups sharing this query
        s2 += __shfl_xor(s2, 16, 64);
        s2 += __shfl_xor(s2, 32, 64);
        xn[qt] = s2;
    }

    // ---- staging: thread (row srow, dim-group scol) of the 32-row tile ----
    const int srow = tid >> 4;          // 0..31
    const int scol = tid & 15;          // dims scol*8 .. +7

    auto convert_store = [&](const float (&v)[8], int gr, int buf) {
        float s2 = 0.f;
        short8 hh, ll;
#pragma unroll
        for (int j = 0; j < 8; ++j) {
            s2 = fmaf(v[j], v[j], s2);
            const unsigned short h = f2bf(v[j]);
            const float r = v[j] - bf2f(h);
            hh[j] = (short)h;
            ll[j] = (short)f2bf(r);
        }
        // row norm: reduce across the 16 lanes (scol) sharing this row
        s2 += __shfl_xor(s2, 1, 64);
        s2 += __shfl_xor(s2, 2, 64);
        s2 += __shfl_xor(s2, 4, 64);
        s2 += __shfl_xor(s2, 8, 64);
        const int idx = srow * 128 + 8 * (scol ^ (srow & 15));   // XOR slot swizzle
        *(short8*)&lhs[buf][idx] = hh;
        *(short8*)&lls[buf][idx] = ll;
        if (scol == 0) lbn[buf][srow] = (gr < rend) ? s2 : INFINITY;
    };

    // prologue: stage tile 0 into buf 0
    {
        const int gr = r0 + srow;
        float v[8] = {0, 0, 0, 0, 0, 0, 0, 0};
        if (gr < NR) {
            const float4 a = *(const float4*)(base + (size_t)gr * D + scol * 8);
            const float4 b = *(const float4*)(base + (size_t)gr * D + scol * 8 + 4);
            v[0] = a.x; v[1] = a.y; v[2] = a.z; v[3] = a.w;
            v[4] = b.x; v[5] = b.y; v[6] = b.z; v[7] = b.w;
        }
        convert_store(v, gr, 0);
    }
    __syncthreads();

    float t0[K], t1[K];
#pragma unroll
    for (int j = 0; j < K; ++j) { t0[j] = INFINITY; t1[j] = INFINITY; }

    int cur = 0;
    for (int ti = 0; ti < NT; ++ti) {
        // prefetch next tile's rows (in flight across the MFMA block, ~1000cy cover)
        float pv[8] = {0, 0, 0, 0, 0, 0, 0, 0};
        int pgr = NR;
        if (ti + 1 < NT) {
            pgr = r0 + (ti + 1) * TR + srow;
            if (pgr < NR) {
                const float4 a = *(const float4*)(base + (size_t)pgr * D + scol * 8);
                const float4 b = *(const float4*)(base + (size_t)pgr * D + scol * 8 + 4);
                pv[0] = a.x; pv[1] = a.y; pv[2] = a.z; pv[3] = a.w;
                pv[4] = b.x; pv[5] = b.y; pv[6] = b.z; pv[7] = b.w;
            }
        }

        // ---- compute on buf[cur]: 2 row-tiles x (4 k-slices x {2qt x 3 terms}) ----
#pragma unroll
        for (int rt = 0; rt < 2; ++rt) {
            const f32x4 bn4 = *(const f32x4*)&lbn[cur][rt * 16 + kg * 4];  // broadcast
            f32x4 acc0 = {0.f, 0.f, 0.f, 0.f};
            f32x4 acc1 = {0.f, 0.f, 0.f, 0.f};
#pragma unroll
            for (int s = 0; s < 4; ++s) {
                const int idx = (rt * 16 + lm) * 128 + 8 * ((s * 4 + kg) ^ lm);
                const short8 Ah = *(const short8*)&lhs[cur][idx];
                const short8 Al = *(const short8*)&lls[cur][idx];
                acc0 = __builtin_amdgcn_mfma_f32_16x16x32_bf16(Ah, Bh[0][s], acc0, 0, 0, 0);
                acc1 = __builtin_amdgcn_mfma_f32_16x16x32_bf16(Ah, Bh[1][s], acc1, 0, 0, 0);
                acc0 = __builtin_amdgcn_mfma_f32_16x16x32_bf16(Ah, Bl[0][s], acc0, 0, 0, 0);
                acc1 = __builtin_amdgcn_mfma_f32_16x16x32_bf16(Ah, Bl[1][s], acc1, 0, 0, 0);
                acc0 = __builtin_amdgcn_mfma_f32_16x16x32_bf16(Al, Bh[0][s], acc0, 0, 0, 0);
                acc1 = __builtin_amdgcn_mfma_f32_16x16x32_bf16(Al, Bh[1][s], acc1, 0, 0, 0);
            }
            // d2' = ||b||^2 + (-2 x.b); ||x||^2 added at writeout (per-lane const)
#pragma unroll
            for (int j = 0; j < 4; ++j) {
                topk_insert(t0, acc0[j] + bn4[j]);
                topk_insert(t1, acc1[j] + bn4[j]);
            }
        }

        // ---- stage next tile into buf[cur^1] (loads have landed by now) ----
        if (ti + 1 < NT) convert_store(pv, pgr, cur ^ 1);
        __syncthreads();
        cur ^= 1;
    }

    // ---- merge the 4 k-group lanes holding the same query (butterfly) ----
#pragma unroll
    for (int st = 16; st <= 32; st <<= 1) {
        float o0[K], o1[K];
#pragma unroll
        for (int j = 0; j < K; ++j) {
            o0[j] = __shfl_xor(t0[j], st, 64);
            o1[j] = __shfl_xor(t1[j], st, 64);
        }
#pragma unroll
        for (int j = 0; j < K; ++j) { topk_insert(t0, o0[j]); topk_insert(t1, o1[j]); }
    }

    if (kg == 0) {
#pragma unroll
        for (int qt = 0; qt < 2; ++qt) {
            const int q = qb * 256 + w * QPW + qt * 16 + lm;
            float* cp = cand + ((size_t)q * NCH + rc) * K;
#pragma unroll
            for (int j = 0; j < K; ++j) {
                const float d2 = (qt ? t1[j] : t0[j]) + xn[qt];
                cp[j] = sqrtf(fmaxf(d2, 0.f));
            }
        }
    }
}

// ---------------- merge 64 per-chunk top-8s per query (already sqrt'd) -------
__global__ __launch_bounds__(256, 4) void knn_merge(const float* __restrict__ cand,
                                                    float* __restrict__ out) {
    const int q = blockIdx.x * blockDim.x + threadIdx.x;
    if (q >= NQ) return;
    const float* cp = cand + (size_t)q * (NCH * K);
    float t[K];
#pragma unroll
    for (int j = 0; j < K; ++j) t[j] = INFINITY;
    for (int i = 0; i < NCH * K; i += 4) {
        const float4 v = *(const float4*)(cp + i);
        topk_insert(t, v.x); topk_insert(t, v.y);
        topk_insert(t, v.z); topk_insert(t, v.w);
    }
#pragma unroll
    for (int j = 0; j < K; ++j) out[(size_t)q * K + j] = t[j];
}

extern "C" void kernel_launch(void* const* d_in, const int* in_sizes, int n_in,
                              void* d_out, int out_size, void* d_ws, size_t ws_size,
                              hipStream_t stream) {
    const float* x    = (const float*)d_in[0];
    const float* base = (const float*)d_in[1];
    float* out  = (float*)d_out;
    float* cand = (float*)d_ws;   // NQ * NCH * K floats = 2 MiB

    knn_mfma<<<4 * NCH, 512, 0, stream>>>(x, base, cand);
    knn_merge<<<(NQ + 255) / 256, 256, 0, stream>>>(cand, out);
}